// Round 16
// baseline (151.469 us; speedup 1.0000x reference)
//
#include <hip/hip_runtime.h>

#define F 64
#define BN_EPS 1e-5f
#define NBLK 1024          // edge chunks for counting sort
#define BSH 7              // bucket = row >> 7 (128 rows/bucket)

typedef __attribute__((ext_vector_type(8))) short bf16x8;
typedef __attribute__((ext_vector_type(4))) float f32x4;

// f32 -> bf16 round-to-nearest-even
static __device__ __forceinline__ unsigned short f2bf(float x) {
    union { float f; unsigned u; } v; v.f = x;
    return (unsigned short)((v.u + 0x7fffu + ((v.u >> 16) & 1u)) >> 16);
}
static __device__ __forceinline__ float bf2f(unsigned short u) {
    union { unsigned u; float f; } v; v.u = (unsigned)u << 16; return v.f;
}

// ---------------- P0: convert x to bf16 (into d_out lower half) --------------
__global__ __launch_bounds__(256) void cvt_kernel(
    const float4* __restrict__ x4,
    ushort4* __restrict__ xb4,
    int total4)
{
    const int stride = gridDim.x * blockDim.x;
    for (int i = blockIdx.x * blockDim.x + threadIdx.x; i < total4; i += stride) {
        const float4 v = x4[i];
        ushort4 o;
        o.x = f2bf(v.x); o.y = f2bf(v.y); o.z = f2bf(v.z); o.w = f2bf(v.w);
        xb4[i] = o;
    }
}

// ---------------- P1: per-chunk bucket histogram (LDS only) ----------------
__global__ __launch_bounds__(256) void p1_count(
    const int* __restrict__ row,
    const int* __restrict__ col,
    int* __restrict__ cnt,          // [NBLK][NB]
    int nEdges, int NB, int C)
{
    __shared__ int hist[1024];      // NB <= 1024
    const int t = threadIdx.x;
    const int b = blockIdx.x;
    for (int u = t; u < NB; u += 256) hist[u] = 0;
    __syncthreads();
    const int e0 = b * C;
    const int e1 = min(e0 + C, nEdges);
    for (int e = e0 + t; e < e1; e += 256) {
        const int r = row[e];
        const int c = col[e];
        if (r != c) atomicAdd(&hist[r >> BSH], 1);
    }
    __syncthreads();
    for (int u = t; u < NB; u += 256) cnt[(size_t)b * NB + u] = hist[u];
}

// ---------------- P2a: column scan of cnt (one block per bucket) -------------
__global__ __launch_bounds__(256) void p2a_colscan(
    int* __restrict__ cnt,
    int* __restrict__ colsum,
    int NB)
{
    __shared__ int vals[NBLK];
    __shared__ int part[256];
    const int u = blockIdx.x;
    const int t = threadIdx.x;
    for (int i = t; i < NBLK; i += 256) vals[i] = cnt[(size_t)i * NB + u];
    __syncthreads();
    int tmp[NBLK / 256];
    int s = 0;
    #pragma unroll
    for (int j = 0; j < NBLK / 256; ++j) { tmp[j] = s; s += vals[t * (NBLK / 256) + j]; }
    part[t] = s;
    __syncthreads();
    for (int off = 1; off < 256; off <<= 1) {
        const int a = (t >= off) ? part[t - off] : 0;
        __syncthreads();
        part[t] += a;
        __syncthreads();
    }
    const int prefix = part[t] - s;
    #pragma unroll
    for (int j = 0; j < NBLK / 256; ++j) vals[t * (NBLK / 256) + j] = prefix + tmp[j];
    __syncthreads();
    for (int i = t; i < NBLK; i += 256) cnt[(size_t)i * NB + u] = vals[i];
    if (t == 255) colsum[u] = part[255];
}

// ---------------- P2b: scan bucket totals -> gstart (single block) -----------
__global__ __launch_bounds__(1024) void p2b_scan(
    const int* __restrict__ colsum,
    int* __restrict__ gstart,
    int* __restrict__ starts,
    int NB, int n)
{
    __shared__ int tmp[1024];
    const int t = threadIdx.x;
    const int v = (t < NB) ? colsum[t] : 0;
    tmp[t] = v;
    __syncthreads();
    for (int off = 1; off < 1024; off <<= 1) {
        const int a = (t >= off) ? tmp[t - off] : 0;
        __syncthreads();
        tmp[t] += a;
        __syncthreads();
    }
    if (t < NB) gstart[t] = tmp[t] - v;
    if (t == 1023) { gstart[NB] = tmp[1023]; starts[n] = tmp[1023]; }
}

// ---------------- P3: scatter edges into bucket-grouped packed array ---------
__global__ __launch_bounds__(256) void p3_scatter(
    const int* __restrict__ row,
    const int* __restrict__ col,
    const int* __restrict__ cnt,
    const int* __restrict__ gstart,
    unsigned* __restrict__ packed,  // (row&127)<<25 | col
    int nEdges, int NB, int C)
{
    __shared__ int cur[1024];
    const int t = threadIdx.x;
    const int b = blockIdx.x;
    for (int u = t; u < NB; u += 256) cur[u] = gstart[u] + cnt[(size_t)b * NB + u];
    __syncthreads();
    const int e0 = b * C;
    const int e1 = min(e0 + C, nEdges);
    for (int e = e0 + t; e < e1; e += 256) {
        const int r = row[e];
        const int c = col[e];
        if (r != c) {
            const int slot = atomicAdd(&cur[r >> BSH], 1);
            packed[slot] = ((unsigned)(r & 127) << 25) | (unsigned)c;
        }
    }
}

// ---------------- P4: per-bucket counting sort -> CSR (starts, col_sorted) ---
__global__ __launch_bounds__(256) void p4_sort(
    const unsigned* __restrict__ packed,
    const int* __restrict__ gstart,
    int* __restrict__ starts,
    int* __restrict__ col_sorted,
    int nNodes, int NB)
{
    __shared__ int hist[128];
    __shared__ int sc[128];
    const int t = threadIdx.x;
    const int u = blockIdx.x;
    const int e0 = gstart[u];
    const int e1 = gstart[u + 1];
    if (t < 128) hist[t] = 0;
    __syncthreads();
    for (int e = e0 + t; e < e1; e += 256) atomicAdd(&hist[packed[e] >> 25], 1);
    __syncthreads();
    if (t < 128) sc[t] = hist[t];
    __syncthreads();
    for (int off = 1; off < 128; off <<= 1) {
        int a = 0;
        if (t < 128 && t >= off) a = sc[t - off];
        __syncthreads();
        if (t < 128) sc[t] += a;
        __syncthreads();
    }
    if (t < 128) {
        const int st = e0 + sc[t] - hist[t];
        sc[t] = st;
        const int node = u * 128 + t;
        if (node < nNodes) starts[node] = st;
    }
    __syncthreads();
    for (int e = e0 + t; e < e1; e += 256) {
        const unsigned p = packed[e];
        const int slot = atomicAdd(&sc[p >> 25], 1);
        col_sorted[slot] = (int)(p & 0x1FFFFFFu);
    }
}

// ---------------- Kernel A: bf16 gather, 2 nodes/wave, uniform 8-deep ---------
// half = lane>>5 selects the node; within a half: g2 = group (2), q = 8B quad
// (16 lanes x 8B = 128B row). Every batch covers 16 edges at 8 loads deep;
// the final partial batch is fma-select predicated (no shallow remainder).
__global__ __launch_bounds__(256) void gather_kernel(
    const ushort4* __restrict__ xb,      // bf16 x, [node][16 x 8B]
    const int* __restrict__ starts,
    const int* __restrict__ col_sorted,  // has +16 ints of slack (speculative tail)
    ushort4* __restrict__ aggb,          // bf16 agg out (ws)
    int nNodes)
{
    const int lane = threadIdx.x & 63;
    const int w    = threadIdx.x >> 6;
    const int half = lane >> 5;          // 0/1: which node of the pair
    const int g2   = (lane >> 4) & 1;    // group within half
    const int q    = lane & 15;          // 8B quad within 128B row

    const int r = (blockIdx.x * 4 + w) * 2 + half;
    const bool act = r < nNodes;
    const int rr = act ? r : nNodes - 1;

    const int s  = starts[rr];
    const int en = act ? starts[rr + 1] : s;   // inactive: empty range

    const ushort4 uself = xb[(size_t)rr * 16 + q];

    float4 a[8];
    #pragma unroll
    for (int j = 0; j < 8; ++j) a[j] = make_float4(0.f, 0.f, 0.f, 0.f);

    int e = s;
    // full 16-edge batches: 8 independent loads deep per node, unpredicated
    for (; e + 16 <= en; e += 16) {
        int c[8];
        #pragma unroll
        for (int j = 0; j < 8; ++j) c[j] = col_sorted[e + g2 + 2 * j];
        #pragma unroll
        for (int j = 0; j < 8; ++j) {
            const ushort4 t = xb[(size_t)c[j] * 16 + q];
            a[j].x += bf2f(t.x); a[j].y += bf2f(t.y);
            a[j].z += bf2f(t.z); a[j].w += bf2f(t.w);
        }
    }
    // final partial batch (1..15 edges), same 8-deep shape, fma-select masked
    if (e < en) {
        #pragma unroll
        for (int j = 0; j < 8; ++j) {
            const int idx = e + g2 + 2 * j;
            const bool vld = idx < en;
            const int c = vld ? col_sorted[idx] : rr;  // slack ints keep any
            const ushort4 t = xb[(size_t)c * 16 + q];  // speculative read in-bounds
            const float sel = vld ? 1.0f : 0.0f;
            a[j].x = fmaf(sel, bf2f(t.x), a[j].x);
            a[j].y = fmaf(sel, bf2f(t.y), a[j].y);
            a[j].z = fmaf(sel, bf2f(t.z), a[j].z);
            a[j].w = fmaf(sel, bf2f(t.w), a[j].w);
        }
    }

    float4 v;
    v.x = ((a[0].x + a[1].x) + (a[2].x + a[3].x)) + ((a[4].x + a[5].x) + (a[6].x + a[7].x));
    v.y = ((a[0].y + a[1].y) + (a[2].y + a[3].y)) + ((a[4].y + a[5].y) + (a[6].y + a[7].y));
    v.z = ((a[0].z + a[1].z) + (a[2].z + a[3].z)) + ((a[4].z + a[5].z) + (a[6].z + a[7].z));
    v.w = ((a[0].w + a[1].w) + (a[2].w + a[3].w)) + ((a[4].w + a[5].w) + (a[6].w + a[7].w));

    // reduce across the two groups of this half (xor 16 stays within the half)
    v.x += __shfl_xor(v.x, 16, 64);
    v.y += __shfl_xor(v.y, 16, 64);
    v.z += __shfl_xor(v.z, 16, 64);
    v.w += __shfl_xor(v.w, 16, 64);

    // add self
    v.x += bf2f(uself.x);
    v.y += bf2f(uself.y);
    v.z += bf2f(uself.z);
    v.w += bf2f(uself.w);

    if (g2 == 0 && act) {
        ushort4 o;
        o.x = f2bf(v.x); o.y = f2bf(v.y); o.z = f2bf(v.z); o.w = f2bf(v.w);
        aggb[(size_t)r * 16 + q] = o;
    }
}

// ---------------- Kernel B: MFMA bf16 MLP + fused BN partial stats ------------
__global__ __launch_bounds__(256) void mlp_kernel(
    const unsigned short* __restrict__ aggbf,   // bf16 agg (ws)
    const float* __restrict__ W1,
    const float* __restrict__ b1,
    const float* __restrict__ W2,
    const float* __restrict__ b2,
    float* __restrict__ out_,                   // d_out (h2, f32)
    float* __restrict__ partial,                // [128][NP]
    int nNodes, int NP)
{
    __shared__ float sH[4][16][68];   // per-wave h1 [node][feat], padded
    __shared__ float sSum[4][64];
    __shared__ float sSq[4][64];

    const int tid  = threadIdx.x;
    const int lane = tid & 63;
    const int w    = tid >> 6;
    const int nb   = lane & 15;
    const int kg   = lane >> 4;
    const int kb   = kg * 8;

    bf16x8 w1f[2][4], w2f[2][4];
    #pragma unroll
    for (int s = 0; s < 2; ++s) {
        #pragma unroll
        for (int c = 0; c < 4; ++c) {
            #pragma unroll
            for (int e = 0; e < 8; ++e) {
                const int k = s * 32 + kb + e;
                w1f[s][c][e] = (short)f2bf(W1[k * 64 + c * 16 + nb]);
                w2f[s][c][e] = (short)f2bf(W2[k * 64 + c * 16 + nb]);
            }
        }
    }

    const int node0 = blockIdx.x * 64 + w * 16;

    int an = node0 + nb;
    if (an >= nNodes) an = nNodes - 1;
    const unsigned short* arow = aggbf + (size_t)an * 64;
    bf16x8 a[2];
    a[0] = *reinterpret_cast<const bf16x8*>(arow + kb);
    a[1] = *reinterpret_cast<const bf16x8*>(arow + 32 + kb);

    #pragma unroll
    for (int c = 0; c < 4; ++c) {
        const float bias = b1[c * 16 + nb];
        f32x4 acc = {bias, bias, bias, bias};
        acc = __builtin_amdgcn_mfma_f32_16x16x32_bf16(a[0], w1f[0][c], acc, 0, 0, 0);
        acc = __builtin_amdgcn_mfma_f32_16x16x32_bf16(a[1], w1f[1][c], acc, 0, 0, 0);
        #pragma unroll
        for (int r = 0; r < 4; ++r)
            sH[w][kg * 4 + r][c * 16 + nb] = fmaxf(acc[r], 0.0f);
    }
    __syncthreads();

    bf16x8 h[2];
    #pragma unroll
    for (int s = 0; s < 2; ++s)
        #pragma unroll
        for (int e = 0; e < 8; ++e)
            h[s][e] = (short)f2bf(sH[w][nb][s * 32 + kb + e]);

    #pragma unroll
    for (int c = 0; c < 4; ++c) {
        const float bias = b2[c * 16 + nb];
        f32x4 acc = {bias, bias, bias, bias};
        acc = __builtin_amdgcn_mfma_f32_16x16x32_bf16(h[0], w2f[0][c], acc, 0, 0, 0);
        acc = __builtin_amdgcn_mfma_f32_16x16x32_bf16(h[1], w2f[1][c], acc, 0, 0, 0);
        float sv = 0.0f, sq = 0.0f;
        #pragma unroll
        for (int r = 0; r < 4; ++r) {
            const int node = node0 + kg * 4 + r;
            const float vv = fmaxf(acc[r], 0.0f);
            if (node < nNodes) {
                out_[(size_t)node * 64 + c * 16 + nb] = vv;
                sv += vv;
                sq = fmaf(vv, vv, sq);
            }
        }
        sv += __shfl_xor(sv, 16, 64);
        sv += __shfl_xor(sv, 32, 64);
        sq += __shfl_xor(sq, 16, 64);
        sq += __shfl_xor(sq, 32, 64);
        if (kg == 0) {
            sSum[w][c * 16 + nb] = sv;
            sSq[w][c * 16 + nb] = sq;
        }
    }
    __syncthreads();

    if (tid < 128) {
        const int f = tid & 63;
        float t;
        if (tid < 64) t = sSum[0][f] + sSum[1][f] + sSum[2][f] + sSum[3][f];
        else          t = sSq[0][f] + sSq[1][f] + sSq[2][f] + sSq[3][f];
        partial[(size_t)tid * NP + blockIdx.x] = t;
    }
}

// ---------------- Kernel C1b: reduce partials -> stats (deterministic) --------
__global__ __launch_bounds__(256) void stats_reduce(
    const float* __restrict__ partial,   // [128][NP]
    float* __restrict__ stats,           // [128]
    int NP)
{
    __shared__ float red[256];
    const int f = blockIdx.x;            // 0..127
    const int t = threadIdx.x;
    float acc = 0.0f;
    for (int i = t; i < NP; i += 256) acc += partial[(size_t)f * NP + i];
    red[t] = acc;
    __syncthreads();
    for (int off = 128; off > 0; off >>= 1) {
        if (t < off) red[t] += red[t + off];
        __syncthreads();
    }
    if (t == 0) stats[f] = red[0];
}

// ---------------- Kernel C2: BN finalize + normalize in place (float4) --------
__global__ __launch_bounds__(256) void bn_normalize_kernel(
    float4* __restrict__ h,
    const float* __restrict__ stats,
    const float* __restrict__ gamma,
    const float* __restrict__ beta,
    int nNodes)
{
    __shared__ float sscale[F];
    __shared__ float sshift[F];
    if (threadIdx.x < F) {
        const int f = threadIdx.x;
        const float invN = 1.0f / (float)nNodes;
        const float mean = stats[f] * invN;
        const float var  = stats[F + f] * invN - mean * mean;
        const float inv  = rsqrtf(var + BN_EPS);
        const float g    = gamma[f];
        sscale[f] = inv * g;
        sshift[f] = beta[f] - mean * inv * g;
    }
    __syncthreads();

    const int total4 = nNodes * (F / 4);
    const int stride = gridDim.x * blockDim.x;
    for (int i = blockIdx.x * blockDim.x + threadIdx.x; i < total4; i += stride) {
        const int f0 = (i & 15) * 4;
        float4 v = h[i];
        v.x = fmaf(v.x, sscale[f0 + 0], sshift[f0 + 0]);
        v.y = fmaf(v.y, sscale[f0 + 1], sshift[f0 + 1]);
        v.z = fmaf(v.z, sscale[f0 + 2], sshift[f0 + 2]);
        v.w = fmaf(v.w, sscale[f0 + 3], sshift[f0 + 3]);
        h[i] = v;
    }
}

extern "C" void kernel_launch(void* const* d_in, const int* in_sizes, int n_in,
                              void* d_out, int out_size, void* d_ws, size_t ws_size,
                              hipStream_t stream)
{
    const float* x     = (const float*)d_in[0];
    const int*   eidx  = (const int*)d_in[1];   // [2, E]: row then col
    const float* W1    = (const float*)d_in[2];
    const float* b1    = (const float*)d_in[3];
    const float* W2    = (const float*)d_in[4];
    const float* b2    = (const float*)d_in[5];
    const float* gamma = (const float*)d_in[6];
    const float* beta  = (const float*)d_in[7];

    const int nNodes = in_sizes[0] / F;
    const int nEdges = in_sizes[1] / 2;
    const int* row = eidx;
    const int* col = eidx + nEdges;

    const int NB = (nNodes + 127) >> BSH;
    const int C  = (nEdges + NBLK - 1) / NBLK;
    const int NP = (nNodes + 63) / 64;         // mlp blocks

    // workspace layout; 256B-aligned. LIFETIME-SIZED UNIONS:
    //   cntX   = cnt[NBLK*NB] (P1-P3)  UNION  col_sorted[nEdges+16] (P4-gather)
    //   packedX= packed[nEdges] (P3-P4) UNION  aggbf[nNodes*64 bf16] (gather-mlp)
    char* wsp = (char*)d_ws;
    auto alloc = [&](size_t bytes) -> char* {
        char* p = wsp;
        wsp += (bytes + 255) & ~(size_t)255;
        return p;
    };
    size_t cnt_bytes = (size_t)NBLK * NB * 4;
    size_t cs_bytes  = ((size_t)nEdges + 16) * 4;
    size_t pk_bytes  = (size_t)nEdges * 4;
    size_t ag_bytes  = (size_t)nNodes * F * 2;

    float*    stats      = (float*)alloc(128 * 4);
    float*    partial    = (float*)alloc((size_t)128 * NP * 4);
    int*      gstart     = (int*)alloc((size_t)(NB + 1) * 4);
    int*      colsum     = (int*)alloc((size_t)NB * 4);
    int*      starts     = (int*)alloc((size_t)(nNodes + 1) * 4);
    char*     cntX       = alloc(cnt_bytes > cs_bytes ? cnt_bytes : cs_bytes);
    int*      cnt        = (int*)cntX;
    int*      col_sorted = (int*)cntX;
    char*     packedX    = alloc(pk_bytes > ag_bytes ? pk_bytes : ag_bytes);
    unsigned* packed     = (unsigned*)packedX;
    unsigned short* aggbf = (unsigned short*)packedX;

    ushort4* xb4 = (ushort4*)d_out;    // bf16 x in d_out until gather completes
    float* hbuf = (float*)d_out;

    cvt_kernel<<<2048, 256, 0, stream>>>((const float4*)x, xb4, nNodes * 16);

    p1_count  <<<NBLK, 256, 0, stream>>>(row, col, cnt, nEdges, NB, C);
    p2a_colscan<<<NB, 256, 0, stream>>>(cnt, colsum, NB);
    p2b_scan  <<<1, 1024, 0, stream>>>(colsum, gstart, starts, NB, nNodes);
    p3_scatter<<<NBLK, 256, 0, stream>>>(row, col, cnt, gstart, packed, nEdges, NB, C);
    p4_sort   <<<NB, 256, 0, stream>>>(packed, gstart, starts, col_sorted, nNodes, NB);

    // A: 2 nodes per wave, 8 nodes per block
    gather_kernel<<<(nNodes + 7) / 8, 256, 0, stream>>>(
        (const ushort4*)xb4, starts, col_sorted, (ushort4*)aggbf, nNodes);

    mlp_kernel<<<NP, 256, 0, stream>>>(
        aggbf, W1, b1, W2, b2, hbuf, partial, nNodes, NP);

    stats_reduce<<<128, 256, 0, stream>>>(partial, stats, NP);
    bn_normalize_kernel<<<2048, 256, 0, stream>>>((float4*)hbuf, stats, gamma, beta, nNodes);
}

// Round 17
// 136.069 us; speedup vs baseline: 1.1132x; 1.1132x over previous
//
#include <hip/hip_runtime.h>

#define F 64
#define BN_EPS 1e-5f
#define NBLK 512           // edge chunks for counting sort (512: 2 blocks/CU, 4x less write amplification than 1024)
#define BSH 7              // bucket = row >> 7 (128 rows/bucket)

typedef __attribute__((ext_vector_type(8))) short bf16x8;
typedef __attribute__((ext_vector_type(4))) float f32x4;

// f32 -> bf16 round-to-nearest-even
static __device__ __forceinline__ unsigned short f2bf(float x) {
    union { float f; unsigned u; } v; v.f = x;
    return (unsigned short)((v.u + 0x7fffu + ((v.u >> 16) & 1u)) >> 16);
}
static __device__ __forceinline__ float bf2f(unsigned short u) {
    union { unsigned u; float f; } v; v.u = (unsigned)u << 16; return v.f;
}

// ---------------- P0: convert x to bf16 (into d_out lower half) --------------
__global__ __launch_bounds__(256) void cvt_kernel(
    const float4* __restrict__ x4,
    ushort4* __restrict__ xb4,
    int total4)
{
    const int stride = gridDim.x * blockDim.x;
    for (int i = blockIdx.x * blockDim.x + threadIdx.x; i < total4; i += stride) {
        const float4 v = x4[i];
        ushort4 o;
        o.x = f2bf(v.x); o.y = f2bf(v.y); o.z = f2bf(v.z); o.w = f2bf(v.w);
        xb4[i] = o;
    }
}

// ---------------- P1: per-chunk bucket histogram (LDS only) ----------------
__global__ __launch_bounds__(256) void p1_count(
    const int* __restrict__ row,
    const int* __restrict__ col,
    int* __restrict__ cnt,          // [NBLK][NB]
    int nEdges, int NB, int C)
{
    __shared__ int hist[1024];      // NB <= 1024
    const int t = threadIdx.x;
    const int b = blockIdx.x;
    for (int u = t; u < NB; u += 256) hist[u] = 0;
    __syncthreads();
    const int e0 = b * C;
    const int e1 = min(e0 + C, nEdges);
    for (int e = e0 + t; e < e1; e += 256) {
        const int r = row[e];
        const int c = col[e];
        if (r != c) atomicAdd(&hist[r >> BSH], 1);
    }
    __syncthreads();
    for (int u = t; u < NB; u += 256) cnt[(size_t)b * NB + u] = hist[u];
}

// ---------------- P2a: column scan of cnt (one block per bucket) -------------
__global__ __launch_bounds__(256) void p2a_colscan(
    int* __restrict__ cnt,
    int* __restrict__ colsum,
    int NB)
{
    __shared__ int vals[NBLK];
    __shared__ int part[256];
    const int u = blockIdx.x;
    const int t = threadIdx.x;
    for (int i = t; i < NBLK; i += 256) vals[i] = cnt[(size_t)i * NB + u];
    __syncthreads();
    int tmp[NBLK / 256];
    int s = 0;
    #pragma unroll
    for (int j = 0; j < NBLK / 256; ++j) { tmp[j] = s; s += vals[t * (NBLK / 256) + j]; }
    part[t] = s;
    __syncthreads();
    for (int off = 1; off < 256; off <<= 1) {
        const int a = (t >= off) ? part[t - off] : 0;
        __syncthreads();
        part[t] += a;
        __syncthreads();
    }
    const int prefix = part[t] - s;
    #pragma unroll
    for (int j = 0; j < NBLK / 256; ++j) vals[t * (NBLK / 256) + j] = prefix + tmp[j];
    __syncthreads();
    for (int i = t; i < NBLK; i += 256) cnt[(size_t)i * NB + u] = vals[i];
    if (t == 255) colsum[u] = part[255];
}

// ---------------- P2b: scan bucket totals -> gstart (single block) -----------
__global__ __launch_bounds__(1024) void p2b_scan(
    const int* __restrict__ colsum,
    int* __restrict__ gstart,
    int* __restrict__ starts,
    int NB, int n)
{
    __shared__ int tmp[1024];
    const int t = threadIdx.x;
    const int v = (t < NB) ? colsum[t] : 0;
    tmp[t] = v;
    __syncthreads();
    for (int off = 1; off < 1024; off <<= 1) {
        const int a = (t >= off) ? tmp[t - off] : 0;
        __syncthreads();
        tmp[t] += a;
        __syncthreads();
    }
    if (t < NB) gstart[t] = tmp[t] - v;
    if (t == 1023) { gstart[NB] = tmp[1023]; starts[n] = tmp[1023]; }
}

// ---------------- P3: scatter edges into bucket-grouped packed array ---------
__global__ __launch_bounds__(256) void p3_scatter(
    const int* __restrict__ row,
    const int* __restrict__ col,
    const int* __restrict__ cnt,
    const int* __restrict__ gstart,
    unsigned* __restrict__ packed,  // (row&127)<<25 | col
    int nEdges, int NB, int C)
{
    __shared__ int cur[1024];
    const int t = threadIdx.x;
    const int b = blockIdx.x;
    for (int u = t; u < NB; u += 256) cur[u] = gstart[u] + cnt[(size_t)b * NB + u];
    __syncthreads();
    const int e0 = b * C;
    const int e1 = min(e0 + C, nEdges);
    for (int e = e0 + t; e < e1; e += 256) {
        const int r = row[e];
        const int c = col[e];
        if (r != c) {
            const int slot = atomicAdd(&cur[r >> BSH], 1);
            packed[slot] = ((unsigned)(r & 127) << 25) | (unsigned)c;
        }
    }
}

// ---------------- P4: per-bucket counting sort -> CSR (starts, col_sorted) ---
__global__ __launch_bounds__(256) void p4_sort(
    const unsigned* __restrict__ packed,
    const int* __restrict__ gstart,
    int* __restrict__ starts,
    int* __restrict__ col_sorted,
    int nNodes, int NB)
{
    __shared__ int hist[128];
    __shared__ int sc[128];
    const int t = threadIdx.x;
    const int u = blockIdx.x;
    const int e0 = gstart[u];
    const int e1 = gstart[u + 1];
    if (t < 128) hist[t] = 0;
    __syncthreads();
    for (int e = e0 + t; e < e1; e += 256) atomicAdd(&hist[packed[e] >> 25], 1);
    __syncthreads();
    if (t < 128) sc[t] = hist[t];
    __syncthreads();
    for (int off = 1; off < 128; off <<= 1) {
        int a = 0;
        if (t < 128 && t >= off) a = sc[t - off];
        __syncthreads();
        if (t < 128) sc[t] += a;
        __syncthreads();
    }
    if (t < 128) {
        const int st = e0 + sc[t] - hist[t];
        sc[t] = st;
        const int node = u * 128 + t;
        if (node < nNodes) starts[node] = st;
    }
    __syncthreads();
    for (int e = e0 + t; e < e1; e += 256) {
        const unsigned p = packed[e];
        const int slot = atomicAdd(&sc[p >> 25], 1);
        col_sorted[slot] = (int)(p & 0x1FFFFFFu);
    }
}

// ---------------- Kernel A: bf16 gather (round-13 structure: 16-lane groups,
// 4-deep, low VGPR). One wave per node; g = lane>>4 (4 groups), q = lane&15
// (8B quad). Occupancy, not depth, is the lever here (r15/r16 evidence).
__global__ __launch_bounds__(256) void gather_kernel(
    const ushort4* __restrict__ xb4,     // bf16 x, [node][16 quads]
    const int* __restrict__ starts,
    const int* __restrict__ col_sorted,
    ushort4* __restrict__ aggb4,         // bf16 agg out (ws)
    int nNodes)
{
    const int lane = threadIdx.x & 63;
    const int w = threadIdx.x >> 6;
    const int r = blockIdx.x * 4 + w;
    if (r >= nNodes) return;

    const int g = lane >> 4;   // 0..3
    const int q = lane & 15;   // 0..15

    const int s  = starts[r];
    const int en = starts[r + 1];

    const ushort4 uself = xb4[(size_t)r * 16 + q];

    float4 a0 = {0,0,0,0}, a1 = {0,0,0,0}, a2 = {0,0,0,0}, a3 = {0,0,0,0};

    int e = s;
    for (; e + 16 <= en; e += 16) {
        const int c0 = col_sorted[e + g];
        const int c1 = col_sorted[e + 4 + g];
        const int c2 = col_sorted[e + 8 + g];
        const int c3 = col_sorted[e + 12 + g];
        const ushort4 t0 = xb4[(size_t)c0 * 16 + q];
        const ushort4 t1 = xb4[(size_t)c1 * 16 + q];
        const ushort4 t2 = xb4[(size_t)c2 * 16 + q];
        const ushort4 t3 = xb4[(size_t)c3 * 16 + q];
        a0.x += bf2f(t0.x); a0.y += bf2f(t0.y); a0.z += bf2f(t0.z); a0.w += bf2f(t0.w);
        a1.x += bf2f(t1.x); a1.y += bf2f(t1.y); a1.z += bf2f(t1.z); a1.w += bf2f(t1.w);
        a2.x += bf2f(t2.x); a2.y += bf2f(t2.y); a2.z += bf2f(t2.z); a2.w += bf2f(t2.w);
        a3.x += bf2f(t3.x); a3.y += bf2f(t3.y); a3.z += bf2f(t3.z); a3.w += bf2f(t3.w);
    }
    for (; e + 4 <= en; e += 4) {
        const int c = col_sorted[e + g];
        const ushort4 t = xb4[(size_t)c * 16 + q];
        a0.x += bf2f(t.x); a0.y += bf2f(t.y); a0.z += bf2f(t.z); a0.w += bf2f(t.w);
    }
    if (e + g < en) {
        const int c = col_sorted[e + g];
        const ushort4 t = xb4[(size_t)c * 16 + q];
        a1.x += bf2f(t.x); a1.y += bf2f(t.y); a1.z += bf2f(t.z); a1.w += bf2f(t.w);
    }

    float4 v;
    v.x = (a0.x + a1.x) + (a2.x + a3.x);
    v.y = (a0.y + a1.y) + (a2.y + a3.y);
    v.z = (a0.z + a1.z) + (a2.z + a3.z);
    v.w = (a0.w + a1.w) + (a2.w + a3.w);
    v.x += __shfl_xor(v.x, 16, 64);
    v.y += __shfl_xor(v.y, 16, 64);
    v.z += __shfl_xor(v.z, 16, 64);
    v.w += __shfl_xor(v.w, 16, 64);
    v.x += __shfl_xor(v.x, 32, 64);
    v.y += __shfl_xor(v.y, 32, 64);
    v.z += __shfl_xor(v.z, 32, 64);
    v.w += __shfl_xor(v.w, 32, 64);
    v.x += bf2f(uself.x);
    v.y += bf2f(uself.y);
    v.z += bf2f(uself.z);
    v.w += bf2f(uself.w);

    if (g == 0) {
        ushort4 o;
        o.x = f2bf(v.x); o.y = f2bf(v.y); o.z = f2bf(v.z); o.w = f2bf(v.w);
        aggb4[(size_t)r * 16 + q] = o;
    }
}

// ---------------- Kernel B: MFMA bf16 MLP + fused BN partial stats ------------
__global__ __launch_bounds__(256) void mlp_kernel(
    const unsigned short* __restrict__ aggbf,   // bf16 agg (ws)
    const float* __restrict__ W1,
    const float* __restrict__ b1,
    const float* __restrict__ W2,
    const float* __restrict__ b2,
    float* __restrict__ out_,                   // d_out (h2, f32)
    float* __restrict__ partial,                // [128][NP]
    int nNodes, int NP)
{
    __shared__ float sH[4][16][68];   // per-wave h1 [node][feat], padded
    __shared__ float sSum[4][64];
    __shared__ float sSq[4][64];

    const int tid  = threadIdx.x;
    const int lane = tid & 63;
    const int w    = tid >> 6;
    const int nb   = lane & 15;
    const int kg   = lane >> 4;
    const int kb   = kg * 8;

    bf16x8 w1f[2][4], w2f[2][4];
    #pragma unroll
    for (int s = 0; s < 2; ++s) {
        #pragma unroll
        for (int c = 0; c < 4; ++c) {
            #pragma unroll
            for (int e = 0; e < 8; ++e) {
                const int k = s * 32 + kb + e;
                w1f[s][c][e] = (short)f2bf(W1[k * 64 + c * 16 + nb]);
                w2f[s][c][e] = (short)f2bf(W2[k * 64 + c * 16 + nb]);
            }
        }
    }

    const int node0 = blockIdx.x * 64 + w * 16;

    int an = node0 + nb;
    if (an >= nNodes) an = nNodes - 1;
    const unsigned short* arow = aggbf + (size_t)an * 64;
    bf16x8 a[2];
    a[0] = *reinterpret_cast<const bf16x8*>(arow + kb);
    a[1] = *reinterpret_cast<const bf16x8*>(arow + 32 + kb);

    #pragma unroll
    for (int c = 0; c < 4; ++c) {
        const float bias = b1[c * 16 + nb];
        f32x4 acc = {bias, bias, bias, bias};
        acc = __builtin_amdgcn_mfma_f32_16x16x32_bf16(a[0], w1f[0][c], acc, 0, 0, 0);
        acc = __builtin_amdgcn_mfma_f32_16x16x32_bf16(a[1], w1f[1][c], acc, 0, 0, 0);
        #pragma unroll
        for (int r = 0; r < 4; ++r)
            sH[w][kg * 4 + r][c * 16 + nb] = fmaxf(acc[r], 0.0f);
    }
    __syncthreads();

    bf16x8 h[2];
    #pragma unroll
    for (int s = 0; s < 2; ++s)
        #pragma unroll
        for (int e = 0; e < 8; ++e)
            h[s][e] = (short)f2bf(sH[w][nb][s * 32 + kb + e]);

    #pragma unroll
    for (int c = 0; c < 4; ++c) {
        const float bias = b2[c * 16 + nb];
        f32x4 acc = {bias, bias, bias, bias};
        acc = __builtin_amdgcn_mfma_f32_16x16x32_bf16(h[0], w2f[0][c], acc, 0, 0, 0);
        acc = __builtin_amdgcn_mfma_f32_16x16x32_bf16(h[1], w2f[1][c], acc, 0, 0, 0);
        float sv = 0.0f, sq = 0.0f;
        #pragma unroll
        for (int r = 0; r < 4; ++r) {
            const int node = node0 + kg * 4 + r;
            const float vv = fmaxf(acc[r], 0.0f);
            if (node < nNodes) {
                out_[(size_t)node * 64 + c * 16 + nb] = vv;
                sv += vv;
                sq = fmaf(vv, vv, sq);
            }
        }
        sv += __shfl_xor(sv, 16, 64);
        sv += __shfl_xor(sv, 32, 64);
        sq += __shfl_xor(sq, 16, 64);
        sq += __shfl_xor(sq, 32, 64);
        if (kg == 0) {
            sSum[w][c * 16 + nb] = sv;
            sSq[w][c * 16 + nb] = sq;
        }
    }
    __syncthreads();

    if (tid < 128) {
        const int f = tid & 63;
        float t;
        if (tid < 64) t = sSum[0][f] + sSum[1][f] + sSum[2][f] + sSum[3][f];
        else          t = sSq[0][f] + sSq[1][f] + sSq[2][f] + sSq[3][f];
        partial[(size_t)tid * NP + blockIdx.x] = t;
    }
}

// ---------------- Kernel C1b: reduce partials -> stats (deterministic) --------
__global__ __launch_bounds__(256) void stats_reduce(
    const float* __restrict__ partial,   // [128][NP]
    float* __restrict__ stats,           // [128]
    int NP)
{
    __shared__ float red[256];
    const int f = blockIdx.x;            // 0..127
    const int t = threadIdx.x;
    float acc = 0.0f;
    for (int i = t; i < NP; i += 256) acc += partial[(size_t)f * NP + i];
    red[t] = acc;
    __syncthreads();
    for (int off = 128; off > 0; off >>= 1) {
        if (t < off) red[t] += red[t + off];
        __syncthreads();
    }
    if (t == 0) stats[f] = red[0];
}

// ---------------- Kernel C2: BN finalize + normalize in place (float4) --------
__global__ __launch_bounds__(256) void bn_normalize_kernel(
    float4* __restrict__ h,
    const float* __restrict__ stats,
    const float* __restrict__ gamma,
    const float* __restrict__ beta,
    int nNodes)
{
    __shared__ float sscale[F];
    __shared__ float sshift[F];
    if (threadIdx.x < F) {
        const int f = threadIdx.x;
        const float invN = 1.0f / (float)nNodes;
        const float mean = stats[f] * invN;
        const float var  = stats[F + f] * invN - mean * mean;
        const float inv  = rsqrtf(var + BN_EPS);
        const float g    = gamma[f];
        sscale[f] = inv * g;
        sshift[f] = beta[f] - mean * inv * g;
    }
    __syncthreads();

    const int total4 = nNodes * (F / 4);
    const int stride = gridDim.x * blockDim.x;
    for (int i = blockIdx.x * blockDim.x + threadIdx.x; i < total4; i += stride) {
        const int f0 = (i & 15) * 4;
        float4 v = h[i];
        v.x = fmaf(v.x, sscale[f0 + 0], sshift[f0 + 0]);
        v.y = fmaf(v.y, sscale[f0 + 1], sshift[f0 + 1]);
        v.z = fmaf(v.z, sscale[f0 + 2], sshift[f0 + 2]);
        v.w = fmaf(v.w, sscale[f0 + 3], sshift[f0 + 3]);
        h[i] = v;
    }
}

extern "C" void kernel_launch(void* const* d_in, const int* in_sizes, int n_in,
                              void* d_out, int out_size, void* d_ws, size_t ws_size,
                              hipStream_t stream)
{
    const float* x     = (const float*)d_in[0];
    const int*   eidx  = (const int*)d_in[1];   // [2, E]: row then col
    const float* W1    = (const float*)d_in[2];
    const float* b1    = (const float*)d_in[3];
    const float* W2    = (const float*)d_in[4];
    const float* b2    = (const float*)d_in[5];
    const float* gamma = (const float*)d_in[6];
    const float* beta  = (const float*)d_in[7];

    const int nNodes = in_sizes[0] / F;
    const int nEdges = in_sizes[1] / 2;
    const int* row = eidx;
    const int* col = eidx + nEdges;

    const int NB = (nNodes + 127) >> BSH;
    const int C  = (nEdges + NBLK - 1) / NBLK;
    const int NP = (nNodes + 63) / 64;         // mlp blocks

    // workspace layout; 256B-aligned. LIFETIME-SIZED UNIONS:
    //   cntX   = cnt[NBLK*NB] (P1-P3)  UNION  col_sorted[nEdges+16] (P4-gather)
    //   packedX= packed[nEdges] (P3-P4) UNION  aggbf[nNodes*64 bf16] (gather-mlp)
    char* wsp = (char*)d_ws;
    auto alloc = [&](size_t bytes) -> char* {
        char* p = wsp;
        wsp += (bytes + 255) & ~(size_t)255;
        return p;
    };
    size_t cnt_bytes = (size_t)NBLK * NB * 4;
    size_t cs_bytes  = ((size_t)nEdges + 16) * 4;
    size_t pk_bytes  = (size_t)nEdges * 4;
    size_t ag_bytes  = (size_t)nNodes * F * 2;

    float*    stats      = (float*)alloc(128 * 4);
    float*    partial    = (float*)alloc((size_t)128 * NP * 4);
    int*      gstart     = (int*)alloc((size_t)(NB + 1) * 4);
    int*      colsum     = (int*)alloc((size_t)NB * 4);
    int*      starts     = (int*)alloc((size_t)(nNodes + 1) * 4);
    char*     cntX       = alloc(cnt_bytes > cs_bytes ? cnt_bytes : cs_bytes);
    int*      cnt        = (int*)cntX;
    int*      col_sorted = (int*)cntX;
    char*     packedX    = alloc(pk_bytes > ag_bytes ? pk_bytes : ag_bytes);
    unsigned* packed     = (unsigned*)packedX;
    unsigned short* aggbf = (unsigned short*)packedX;

    ushort4* xb4 = (ushort4*)d_out;    // bf16 x in d_out until gather completes
    float* hbuf = (float*)d_out;

    cvt_kernel<<<2048, 256, 0, stream>>>((const float4*)x, xb4, nNodes * 16);

    p1_count  <<<NBLK, 256, 0, stream>>>(row, col, cnt, nEdges, NB, C);
    p2a_colscan<<<NB, 256, 0, stream>>>(cnt, colsum, NB);
    p2b_scan  <<<1, 1024, 0, stream>>>(colsum, gstart, starts, NB, nNodes);
    p3_scatter<<<NBLK, 256, 0, stream>>>(row, col, cnt, gstart, packed, nEdges, NB, C);
    p4_sort   <<<NB, 256, 0, stream>>>(packed, gstart, starts, col_sorted, nNodes, NB);

    // A: one wave per node (round-13 proven shape)
    gather_kernel<<<(nNodes + 3) / 4, 256, 0, stream>>>(
        (const ushort4*)xb4, starts, col_sorted, (ushort4*)aggbf, nNodes);

    mlp_kernel<<<NP, 256, 0, stream>>>(
        aggbf, W1, b1, W2, b2, hbuf, partial, nNodes, NP);

    stats_reduce<<<128, 256, 0, stream>>>(partial, stats, NP);
    bn_normalize_kernel<<<2048, 256, 0, stream>>>((float4*)hbuf, stats, gamma, beta, nNodes);
}

// Round 18
// 132.270 us; speedup vs baseline: 1.1451x; 1.0287x over previous
//
#include <hip/hip_runtime.h>

#define F 64
#define BN_EPS 1e-5f
#define NBLK 512           // edge chunks for counting sort
#define BSH 7              // bucket = row >> 7 (128 rows/bucket)

typedef __attribute__((ext_vector_type(8))) short bf16x8;
typedef __attribute__((ext_vector_type(4))) float f32x4;

// f32 -> bf16 round-to-nearest-even
static __device__ __forceinline__ unsigned short f2bf(float x) {
    union { float f; unsigned u; } v; v.f = x;
    return (unsigned short)((v.u + 0x7fffu + ((v.u >> 16) & 1u)) >> 16);
}
static __device__ __forceinline__ float bf2f(unsigned short u) {
    union { unsigned u; float f; } v; v.u = (unsigned)u << 16; return v.f;
}

// ---------------- P1: fused x->bf16 convert + per-chunk bucket histogram -----
__global__ __launch_bounds__(256) void p1_count(
    const float4* __restrict__ x4,
    ushort4* __restrict__ xb4,      // d_out lower half
    const int* __restrict__ row,
    const int* __restrict__ col,
    int* __restrict__ cnt,          // [NBLK][NB]
    int nEdges, int NB, int C, int total4)
{
    __shared__ int hist[1024];      // NB <= 1024
    const int t = threadIdx.x;
    const int b = blockIdx.x;
    for (int u = t; u < NB; u += 256) hist[u] = 0;

    // fused cvt: grid-stride over x
    for (int i = b * 256 + t; i < total4; i += NBLK * 256) {
        const float4 v = x4[i];
        ushort4 o;
        o.x = f2bf(v.x); o.y = f2bf(v.y); o.z = f2bf(v.z); o.w = f2bf(v.w);
        xb4[i] = o;
    }
    __syncthreads();

    const int e0 = b * C;
    const int e1 = min(e0 + C, nEdges);
    for (int e = e0 + t; e < e1; e += 256) {
        const int r = row[e];
        const int c = col[e];
        if (r != c) atomicAdd(&hist[r >> BSH], 1);
    }
    __syncthreads();
    for (int u = t; u < NB; u += 256) cnt[(size_t)b * NB + u] = hist[u];
}

// ---------------- P2a: column scan of cnt (one block per bucket) -------------
__global__ __launch_bounds__(256) void p2a_colscan(
    int* __restrict__ cnt,
    int* __restrict__ colsum,
    int NB)
{
    __shared__ int vals[NBLK];
    __shared__ int part[256];
    const int u = blockIdx.x;
    const int t = threadIdx.x;
    for (int i = t; i < NBLK; i += 256) vals[i] = cnt[(size_t)i * NB + u];
    __syncthreads();
    int tmp[NBLK / 256];
    int s = 0;
    #pragma unroll
    for (int j = 0; j < NBLK / 256; ++j) { tmp[j] = s; s += vals[t * (NBLK / 256) + j]; }
    part[t] = s;
    __syncthreads();
    for (int off = 1; off < 256; off <<= 1) {
        const int a = (t >= off) ? part[t - off] : 0;
        __syncthreads();
        part[t] += a;
        __syncthreads();
    }
    const int prefix = part[t] - s;
    #pragma unroll
    for (int j = 0; j < NBLK / 256; ++j) vals[t * (NBLK / 256) + j] = prefix + tmp[j];
    __syncthreads();
    for (int i = t; i < NBLK; i += 256) cnt[(size_t)i * NB + u] = vals[i];
    if (t == 255) colsum[u] = part[255];
}

// ---------------- P2b: scan bucket totals -> gstart (single block) -----------
__global__ __launch_bounds__(1024) void p2b_scan(
    const int* __restrict__ colsum,
    int* __restrict__ gstart,
    int* __restrict__ starts,
    int NB, int n)
{
    __shared__ int tmp[1024];
    const int t = threadIdx.x;
    const int v = (t < NB) ? colsum[t] : 0;
    tmp[t] = v;
    __syncthreads();
    for (int off = 1; off < 1024; off <<= 1) {
        const int a = (t >= off) ? tmp[t - off] : 0;
        __syncthreads();
        tmp[t] += a;
        __syncthreads();
    }
    if (t < NB) gstart[t] = tmp[t] - v;
    if (t == 1023) { gstart[NB] = tmp[1023]; starts[n] = tmp[1023]; }
}

// ---------------- P3: scatter edges into bucket-grouped packed array ---------
__global__ __launch_bounds__(256) void p3_scatter(
    const int* __restrict__ row,
    const int* __restrict__ col,
    const int* __restrict__ cnt,
    const int* __restrict__ gstart,
    unsigned* __restrict__ packed,  // (row&127)<<25 | col
    int nEdges, int NB, int C)
{
    __shared__ int cur[1024];
    const int t = threadIdx.x;
    const int b = blockIdx.x;
    for (int u = t; u < NB; u += 256) cur[u] = gstart[u] + cnt[(size_t)b * NB + u];
    __syncthreads();
    const int e0 = b * C;
    const int e1 = min(e0 + C, nEdges);
    for (int e = e0 + t; e < e1; e += 256) {
        const int r = row[e];
        const int c = col[e];
        if (r != c) {
            const int slot = atomicAdd(&cur[r >> BSH], 1);
            packed[slot] = ((unsigned)(r & 127) << 25) | (unsigned)c;
        }
    }
}

// ---------------- P4: per-bucket counting sort -> CSR (starts, col_sorted) ---
__global__ __launch_bounds__(256) void p4_sort(
    const unsigned* __restrict__ packed,
    const int* __restrict__ gstart,
    int* __restrict__ starts,
    int* __restrict__ col_sorted,
    int nNodes, int NB)
{
    __shared__ int hist[128];
    __shared__ int sc[128];
    const int t = threadIdx.x;
    const int u = blockIdx.x;
    const int e0 = gstart[u];
    const int e1 = gstart[u + 1];
    if (t < 128) hist[t] = 0;
    __syncthreads();
    for (int e = e0 + t; e < e1; e += 256) atomicAdd(&hist[packed[e] >> 25], 1);
    __syncthreads();
    if (t < 128) sc[t] = hist[t];
    __syncthreads();
    for (int off = 1; off < 128; off <<= 1) {
        int a = 0;
        if (t < 128 && t >= off) a = sc[t - off];
        __syncthreads();
        if (t < 128) sc[t] += a;
        __syncthreads();
    }
    if (t < 128) {
        const int st = e0 + sc[t] - hist[t];
        sc[t] = st;
        const int node = u * 128 + t;
        if (node < nNodes) starts[node] = st;
    }
    __syncthreads();
    for (int e = e0 + t; e < e1; e += 256) {
        const unsigned p = packed[e];
        const int slot = atomicAdd(&sc[p >> 25], 1);
        col_sorted[slot] = (int)(p & 0x1FFFFFFu);
    }
}

// ---------------- Kernel A: bf16 gather (r13 proven shape) --------------------
__global__ __launch_bounds__(256) void gather_kernel(
    const ushort4* __restrict__ xb4,     // bf16 x, [node][16 quads]
    const int* __restrict__ starts,
    const int* __restrict__ col_sorted,
    ushort4* __restrict__ aggb4,         // bf16 agg out (ws)
    int nNodes)
{
    const int lane = threadIdx.x & 63;
    const int w = threadIdx.x >> 6;
    const int r = blockIdx.x * 4 + w;
    if (r >= nNodes) return;

    const int g = lane >> 4;   // 0..3
    const int q = lane & 15;   // 0..15

    const int s  = starts[r];
    const int en = starts[r + 1];

    const ushort4 uself = xb4[(size_t)r * 16 + q];

    float4 a0 = {0,0,0,0}, a1 = {0,0,0,0}, a2 = {0,0,0,0}, a3 = {0,0,0,0};

    int e = s;
    for (; e + 16 <= en; e += 16) {
        const int c0 = col_sorted[e + g];
        const int c1 = col_sorted[e + 4 + g];
        const int c2 = col_sorted[e + 8 + g];
        const int c3 = col_sorted[e + 12 + g];
        const ushort4 t0 = xb4[(size_t)c0 * 16 + q];
        const ushort4 t1 = xb4[(size_t)c1 * 16 + q];
        const ushort4 t2 = xb4[(size_t)c2 * 16 + q];
        const ushort4 t3 = xb4[(size_t)c3 * 16 + q];
        a0.x += bf2f(t0.x); a0.y += bf2f(t0.y); a0.z += bf2f(t0.z); a0.w += bf2f(t0.w);
        a1.x += bf2f(t1.x); a1.y += bf2f(t1.y); a1.z += bf2f(t1.z); a1.w += bf2f(t1.w);
        a2.x += bf2f(t2.x); a2.y += bf2f(t2.y); a2.z += bf2f(t2.z); a2.w += bf2f(t2.w);
        a3.x += bf2f(t3.x); a3.y += bf2f(t3.y); a3.z += bf2f(t3.z); a3.w += bf2f(t3.w);
    }
    for (; e + 4 <= en; e += 4) {
        const int c = col_sorted[e + g];
        const ushort4 t = xb4[(size_t)c * 16 + q];
        a0.x += bf2f(t.x); a0.y += bf2f(t.y); a0.z += bf2f(t.z); a0.w += bf2f(t.w);
    }
    if (e + g < en) {
        const int c = col_sorted[e + g];
        const ushort4 t = xb4[(size_t)c * 16 + q];
        a1.x += bf2f(t.x); a1.y += bf2f(t.y); a1.z += bf2f(t.z); a1.w += bf2f(t.w);
    }

    float4 v;
    v.x = (a0.x + a1.x) + (a2.x + a3.x);
    v.y = (a0.y + a1.y) + (a2.y + a3.y);
    v.z = (a0.z + a1.z) + (a2.z + a3.z);
    v.w = (a0.w + a1.w) + (a2.w + a3.w);
    v.x += __shfl_xor(v.x, 16, 64);
    v.y += __shfl_xor(v.y, 16, 64);
    v.z += __shfl_xor(v.z, 16, 64);
    v.w += __shfl_xor(v.w, 16, 64);
    v.x += __shfl_xor(v.x, 32, 64);
    v.y += __shfl_xor(v.y, 32, 64);
    v.z += __shfl_xor(v.z, 32, 64);
    v.w += __shfl_xor(v.w, 32, 64);
    v.x += bf2f(uself.x);
    v.y += bf2f(uself.y);
    v.z += bf2f(uself.z);
    v.w += bf2f(uself.w);

    if (g == 0) {
        ushort4 o;
        o.x = f2bf(v.x); o.y = f2bf(v.y); o.z = f2bf(v.z); o.w = f2bf(v.w);
        aggb4[(size_t)r * 16 + q] = o;
    }
}

// ---------------- Kernel B: MFMA bf16 MLP + fused BN stats, bf16 h2 in place --
// io holds agg (bf16) on entry, h2 (bf16) on exit. Block-private rows: each
// block reads only its own nodes' rows before writing them (clamped reads from
// the final block may see torn data but are fully discarded).
__global__ __launch_bounds__(256) void mlp_kernel(
    unsigned short* io,                         // bf16 agg -> bf16 h2 (ws)
    const float* __restrict__ W1,
    const float* __restrict__ b1,
    const float* __restrict__ W2,
    const float* __restrict__ b2,
    float* __restrict__ partial,                // [128][NP]
    int nNodes, int NP)
{
    __shared__ float sH[4][16][68];   // per-wave h1 [node][feat], padded
    __shared__ float sSum[4][64];
    __shared__ float sSq[4][64];

    const int tid  = threadIdx.x;
    const int lane = tid & 63;
    const int w    = tid >> 6;
    const int nb   = lane & 15;
    const int kg   = lane >> 4;
    const int kb   = kg * 8;

    bf16x8 w1f[2][4], w2f[2][4];
    #pragma unroll
    for (int s = 0; s < 2; ++s) {
        #pragma unroll
        for (int c = 0; c < 4; ++c) {
            #pragma unroll
            for (int e = 0; e < 8; ++e) {
                const int k = s * 32 + kb + e;
                w1f[s][c][e] = (short)f2bf(W1[k * 64 + c * 16 + nb]);
                w2f[s][c][e] = (short)f2bf(W2[k * 64 + c * 16 + nb]);
            }
        }
    }

    const int node0 = blockIdx.x * 64 + w * 16;

    int an = node0 + nb;
    if (an >= nNodes) an = nNodes - 1;
    const unsigned short* arow = io + (size_t)an * 64;
    bf16x8 a[2];
    a[0] = *reinterpret_cast<const bf16x8*>(arow + kb);
    a[1] = *reinterpret_cast<const bf16x8*>(arow + 32 + kb);

    #pragma unroll
    for (int c = 0; c < 4; ++c) {
        const float bias = b1[c * 16 + nb];
        f32x4 acc = {bias, bias, bias, bias};
        acc = __builtin_amdgcn_mfma_f32_16x16x32_bf16(a[0], w1f[0][c], acc, 0, 0, 0);
        acc = __builtin_amdgcn_mfma_f32_16x16x32_bf16(a[1], w1f[1][c], acc, 0, 0, 0);
        #pragma unroll
        for (int r = 0; r < 4; ++r)
            sH[w][kg * 4 + r][c * 16 + nb] = fmaxf(acc[r], 0.0f);
    }
    __syncthreads();

    bf16x8 h[2];
    #pragma unroll
    for (int s = 0; s < 2; ++s)
        #pragma unroll
        for (int e = 0; e < 8; ++e)
            h[s][e] = (short)f2bf(sH[w][nb][s * 32 + kb + e]);

    #pragma unroll
    for (int c = 0; c < 4; ++c) {
        const float bias = b2[c * 16 + nb];
        f32x4 acc = {bias, bias, bias, bias};
        acc = __builtin_amdgcn_mfma_f32_16x16x32_bf16(h[0], w2f[0][c], acc, 0, 0, 0);
        acc = __builtin_amdgcn_mfma_f32_16x16x32_bf16(h[1], w2f[1][c], acc, 0, 0, 0);
        float sv = 0.0f, sq = 0.0f;
        #pragma unroll
        for (int r = 0; r < 4; ++r) {
            const int node = node0 + kg * 4 + r;
            const float vv = fmaxf(acc[r], 0.0f);
            if (node < nNodes) {
                io[(size_t)node * 64 + c * 16 + nb] = f2bf(vv);
                sv += vv;
                sq = fmaf(vv, vv, sq);
            }
        }
        sv += __shfl_xor(sv, 16, 64);
        sv += __shfl_xor(sv, 32, 64);
        sq += __shfl_xor(sq, 16, 64);
        sq += __shfl_xor(sq, 32, 64);
        if (kg == 0) {
            sSum[w][c * 16 + nb] = sv;
            sSq[w][c * 16 + nb] = sq;
        }
    }
    __syncthreads();

    if (tid < 128) {
        const int f = tid & 63;
        float t;
        if (tid < 64) t = sSum[0][f] + sSum[1][f] + sSum[2][f] + sSum[3][f];
        else          t = sSq[0][f] + sSq[1][f] + sSq[2][f] + sSq[3][f];
        partial[(size_t)tid * NP + blockIdx.x] = t;
    }
}

// ---------------- Kernel C1b: reduce partials -> scale/shift (deterministic) --
// Block f (0..63) reduces sum row f and sumsq row 64+f, then emits
// ss[f] = gamma*inv_std, ss[64+f] = beta - mean*gamma*inv_std.
__global__ __launch_bounds__(256) void stats_reduce(
    const float* __restrict__ partial,   // [128][NP]
    const float* __restrict__ gamma,
    const float* __restrict__ beta,
    float* __restrict__ ss,              // [128]: scale | shift
    int NP, float invN)
{
    __shared__ float rs[256];
    __shared__ float rq[256];
    const int f = blockIdx.x;            // 0..63
    const int t = threadIdx.x;
    float as = 0.0f, aq = 0.0f;
    for (int i = t; i < NP; i += 256) {
        as += partial[(size_t)f * NP + i];
        aq += partial[(size_t)(64 + f) * NP + i];
    }
    rs[t] = as;
    rq[t] = aq;
    __syncthreads();
    for (int off = 128; off > 0; off >>= 1) {
        if (t < off) { rs[t] += rs[t + off]; rq[t] += rq[t + off]; }
        __syncthreads();
    }
    if (t == 0) {
        const float mean = rs[0] * invN;
        const float var  = rq[0] * invN - mean * mean;
        const float inv  = rsqrtf(var + BN_EPS);
        const float g    = gamma[f];
        ss[f]      = inv * g;
        ss[64 + f] = beta[f] - mean * inv * g;
    }
}

// ---------------- Kernel C2: BN apply — bf16 h2 in, f32 out -------------------
__global__ __launch_bounds__(256) void bn_normalize_kernel(
    const ushort4* __restrict__ h2b,     // bf16 h2 (ws)
    const float* __restrict__ ss,        // [128]: scale | shift
    float4* __restrict__ out4,           // d_out
    int nNodes)
{
    __shared__ float sscale[F];
    __shared__ float sshift[F];
    if (threadIdx.x < F) {
        sscale[threadIdx.x] = ss[threadIdx.x];
        sshift[threadIdx.x] = ss[64 + threadIdx.x];
    }
    __syncthreads();

    const int total = nNodes * 16;       // ushort4 units (4 feats each)
    const int stride = gridDim.x * blockDim.x;
    for (int i = blockIdx.x * blockDim.x + threadIdx.x; i < total; i += stride) {
        const int f0 = (i & 15) * 4;
        const ushort4 u = h2b[i];
        float4 v;
        v.x = fmaf(bf2f(u.x), sscale[f0 + 0], sshift[f0 + 0]);
        v.y = fmaf(bf2f(u.y), sscale[f0 + 1], sshift[f0 + 1]);
        v.z = fmaf(bf2f(u.z), sscale[f0 + 2], sshift[f0 + 2]);
        v.w = fmaf(bf2f(u.w), sscale[f0 + 3], sshift[f0 + 3]);
        out4[i] = v;
    }
}

extern "C" void kernel_launch(void* const* d_in, const int* in_sizes, int n_in,
                              void* d_out, int out_size, void* d_ws, size_t ws_size,
                              hipStream_t stream)
{
    const float* x     = (const float*)d_in[0];
    const int*   eidx  = (const int*)d_in[1];   // [2, E]: row then col
    const float* W1    = (const float*)d_in[2];
    const float* b1    = (const float*)d_in[3];
    const float* W2    = (const float*)d_in[4];
    const float* b2    = (const float*)d_in[5];
    const float* gamma = (const float*)d_in[6];
    const float* beta  = (const float*)d_in[7];

    const int nNodes = in_sizes[0] / F;
    const int nEdges = in_sizes[1] / 2;
    const int* row = eidx;
    const int* col = eidx + nEdges;

    const int NB = (nNodes + 127) >> BSH;
    const int C  = (nEdges + NBLK - 1) / NBLK;
    const int NP = (nNodes + 63) / 64;         // mlp blocks

    // workspace layout; 256B-aligned. LIFETIME-SIZED UNIONS:
    //   cntX   = cnt[NBLK*NB] (P1-P3)  UNION  col_sorted[nEdges+16] (P4-gather)
    //   packedX= packed[nEdges] (P3-P4) UNION  agg/h2 bf16 [nNodes*64] (gather-bn)
    char* wsp = (char*)d_ws;
    auto alloc = [&](size_t bytes) -> char* {
        char* p = wsp;
        wsp += (bytes + 255) & ~(size_t)255;
        return p;
    };
    size_t cnt_bytes = (size_t)NBLK * NB * 4;
    size_t cs_bytes  = ((size_t)nEdges + 16) * 4;
    size_t pk_bytes  = (size_t)nEdges * 4;
    size_t ag_bytes  = (size_t)nNodes * F * 2;

    float*    ss         = (float*)alloc(128 * 4);
    float*    partial    = (float*)alloc((size_t)128 * NP * 4);
    int*      gstart     = (int*)alloc((size_t)(NB + 1) * 4);
    int*      colsum     = (int*)alloc((size_t)NB * 4);
    int*      starts     = (int*)alloc((size_t)(nNodes + 1) * 4);
    char*     cntX       = alloc(cnt_bytes > cs_bytes ? cnt_bytes : cs_bytes);
    int*      cnt        = (int*)cntX;
    int*      col_sorted = (int*)cntX;
    char*     packedX    = alloc(pk_bytes > ag_bytes ? pk_bytes : ag_bytes);
    unsigned* packed     = (unsigned*)packedX;
    unsigned short* aggbf = (unsigned short*)packedX;

    ushort4* xb4 = (ushort4*)d_out;    // bf16 x in d_out until gather completes
    float4* out4 = (float4*)d_out;

    // P1 (fused cvt + histogram)
    p1_count  <<<NBLK, 256, 0, stream>>>((const float4*)x, xb4, row, col, cnt,
                                         nEdges, NB, C, nNodes * 16);
    p2a_colscan<<<NB, 256, 0, stream>>>(cnt, colsum, NB);
    p2b_scan  <<<1, 1024, 0, stream>>>(colsum, gstart, starts, NB, nNodes);
    p3_scatter<<<NBLK, 256, 0, stream>>>(row, col, cnt, gstart, packed, nEdges, NB, C);
    p4_sort   <<<NB, 256, 0, stream>>>(packed, gstart, starts, col_sorted, nNodes, NB);

    gather_kernel<<<(nNodes + 3) / 4, 256, 0, stream>>>(
        (const ushort4*)xb4, starts, col_sorted, (ushort4*)aggbf, nNodes);

    mlp_kernel<<<NP, 256, 0, stream>>>(
        aggbf, W1, b1, W2, b2, partial, nNodes, NP);

    stats_reduce<<<64, 256, 0, stream>>>(partial, gamma, beta, ss, NP,
                                         1.0f / (float)nNodes);

    bn_normalize_kernel<<<2048, 256, 0, stream>>>(
        (const ushort4*)aggbf, ss, out4, nNodes);
}

// Round 19
// 129.903 us; speedup vs baseline: 1.1660x; 1.0182x over previous
//
#include <hip/hip_runtime.h>

#define F 64
#define BN_EPS 1e-5f
#define NBLK 512           // edge chunks for counting sort
#define BSH 7              // bucket = row >> 7 (128 rows/bucket)

typedef __attribute__((ext_vector_type(8))) short bf16x8;
typedef __attribute__((ext_vector_type(4))) float f32x4;

// f32 -> bf16 round-to-nearest-even
static __device__ __forceinline__ unsigned short f2bf(float x) {
    union { float f; unsigned u; } v; v.f = x;
    return (unsigned short)((v.u + 0x7fffu + ((v.u >> 16) & 1u)) >> 16);
}
static __device__ __forceinline__ float bf2f(unsigned short u) {
    union { unsigned u; float f; } v; v.u = (unsigned)u << 16; return v.f;
}

// ---------------- P1: fused x->bf16 convert + per-chunk bucket histogram -----
__global__ __launch_bounds__(256) void p1_count(
    const float4* __restrict__ x4,
    ushort4* __restrict__ xb4,      // d_out lower half
    const int* __restrict__ row,
    const int* __restrict__ col,
    int* __restrict__ cnt,          // [NBLK][NB]
    int nEdges, int NB, int C, int total4)
{
    __shared__ int hist[1024];      // NB <= 1024
    const int t = threadIdx.x;
    const int b = blockIdx.x;
    for (int u = t; u < NB; u += 256) hist[u] = 0;

    // fused cvt: grid-stride over x
    for (int i = b * 256 + t; i < total4; i += NBLK * 256) {
        const float4 v = x4[i];
        ushort4 o;
        o.x = f2bf(v.x); o.y = f2bf(v.y); o.z = f2bf(v.z); o.w = f2bf(v.w);
        xb4[i] = o;
    }
    __syncthreads();

    const int e0 = b * C;
    const int e1 = min(e0 + C, nEdges);
    for (int e = e0 + t; e < e1; e += 256) {
        const int r = row[e];
        const int c = col[e];
        if (r != c) atomicAdd(&hist[r >> BSH], 1);
    }
    __syncthreads();
    for (int u = t; u < NB; u += 256) cnt[(size_t)b * NB + u] = hist[u];
}

// ---------------- P2a: column scan of cnt (one block per bucket) -------------
__global__ __launch_bounds__(256) void p2a_colscan(
    int* __restrict__ cnt,
    int* __restrict__ colsum,
    int NB)
{
    __shared__ int vals[NBLK];
    __shared__ int part[256];
    const int u = blockIdx.x;
    const int t = threadIdx.x;
    for (int i = t; i < NBLK; i += 256) vals[i] = cnt[(size_t)i * NB + u];
    __syncthreads();
    int tmp[NBLK / 256];
    int s = 0;
    #pragma unroll
    for (int j = 0; j < NBLK / 256; ++j) { tmp[j] = s; s += vals[t * (NBLK / 256) + j]; }
    part[t] = s;
    __syncthreads();
    for (int off = 1; off < 256; off <<= 1) {
        const int a = (t >= off) ? part[t - off] : 0;
        __syncthreads();
        part[t] += a;
        __syncthreads();
    }
    const int prefix = part[t] - s;
    #pragma unroll
    for (int j = 0; j < NBLK / 256; ++j) vals[t * (NBLK / 256) + j] = prefix + tmp[j];
    __syncthreads();
    for (int i = t; i < NBLK; i += 256) cnt[(size_t)i * NB + u] = vals[i];
    if (t == 255) colsum[u] = part[255];
}

// ---------------- P3: scatter edges (p2b's scan folded in, done per block) ---
__global__ __launch_bounds__(256) void p3_scatter(
    const int* __restrict__ row,
    const int* __restrict__ col,
    const int* __restrict__ cnt,
    const int* __restrict__ colsum,   // [NB] bucket totals (from p2a)
    int* __restrict__ gstart,         // [NB+1] — block 0 writes (for p4)
    int* __restrict__ starts_top,     // &starts[nNodes] — block 0 writes total
    unsigned* __restrict__ packed,    // (row&127)<<25 | col
    int nEdges, int NB, int C)
{
    __shared__ int gs[1024];          // exclusive scan of colsum
    __shared__ int part[256];
    __shared__ int cur[1024];
    const int t = threadIdx.x;
    const int b = blockIdx.x;

    // local exclusive scan of colsum[0..NB), 4 elems/thread (NB <= 1024)
    int loc[4];
    int s = 0;
    #pragma unroll
    for (int j = 0; j < 4; ++j) {
        const int i = t * 4 + j;
        loc[j] = s;
        s += (i < NB) ? colsum[i] : 0;
    }
    part[t] = s;
    __syncthreads();
    for (int off = 1; off < 256; off <<= 1) {
        const int a = (t >= off) ? part[t - off] : 0;
        __syncthreads();
        part[t] += a;
        __syncthreads();
    }
    const int prefix = part[t] - s;
    #pragma unroll
    for (int j = 0; j < 4; ++j) {
        const int i = t * 4 + j;
        if (i < NB) gs[i] = prefix + loc[j];
    }
    __syncthreads();

    // init cursors; block 0 materializes gstart/starts[n] for p4 (stream-ordered)
    for (int u = t; u < NB; u += 256) cur[u] = gs[u] + cnt[(size_t)b * NB + u];
    if (b == 0) {
        for (int u = t; u < NB; u += 256) gstart[u] = gs[u];
        if (t == 255) { gstart[NB] = part[255]; starts_top[0] = part[255]; }
    }
    __syncthreads();

    const int e0 = b * C;
    const int e1 = min(e0 + C, nEdges);
    for (int e = e0 + t; e < e1; e += 256) {
        const int r = row[e];
        const int c = col[e];
        if (r != c) {
            const int slot = atomicAdd(&cur[r >> BSH], 1);
            packed[slot] = ((unsigned)(r & 127) << 25) | (unsigned)c;
        }
    }
}

// ---------------- P4: per-bucket counting sort -> CSR (starts, col_sorted) ---
__global__ __launch_bounds__(256) void p4_sort(
    const unsigned* __restrict__ packed,
    const int* __restrict__ gstart,
    int* __restrict__ starts,
    int* __restrict__ col_sorted,
    int nNodes, int NB)
{
    __shared__ int hist[128];
    __shared__ int sc[128];
    const int t = threadIdx.x;
    const int u = blockIdx.x;
    const int e0 = gstart[u];
    const int e1 = gstart[u + 1];
    if (t < 128) hist[t] = 0;
    __syncthreads();
    for (int e = e0 + t; e < e1; e += 256) atomicAdd(&hist[packed[e] >> 25], 1);
    __syncthreads();
    if (t < 128) sc[t] = hist[t];
    __syncthreads();
    for (int off = 1; off < 128; off <<= 1) {
        int a = 0;
        if (t < 128 && t >= off) a = sc[t - off];
        __syncthreads();
        if (t < 128) sc[t] += a;
        __syncthreads();
    }
    if (t < 128) {
        const int st = e0 + sc[t] - hist[t];
        sc[t] = st;
        const int node = u * 128 + t;
        if (node < nNodes) starts[node] = st;
    }
    __syncthreads();
    for (int e = e0 + t; e < e1; e += 256) {
        const unsigned p = packed[e];
        const int slot = atomicAdd(&sc[p >> 25], 1);
        col_sorted[slot] = (int)(p & 0x1FFFFFFu);
    }
}

// ---------------- Kernel A: bf16 gather (r13 proven shape) --------------------
__global__ __launch_bounds__(256) void gather_kernel(
    const ushort4* __restrict__ xb4,     // bf16 x, [node][16 quads]
    const int* __restrict__ starts,
    const int* __restrict__ col_sorted,
    ushort4* __restrict__ aggb4,         // bf16 agg out (ws)
    int nNodes)
{
    const int lane = threadIdx.x & 63;
    const int w = threadIdx.x >> 6;
    const int r = blockIdx.x * 4 + w;
    if (r >= nNodes) return;

    const int g = lane >> 4;   // 0..3
    const int q = lane & 15;   // 0..15

    const int s  = starts[r];
    const int en = starts[r + 1];

    const ushort4 uself = xb4[(size_t)r * 16 + q];

    float4 a0 = {0,0,0,0}, a1 = {0,0,0,0}, a2 = {0,0,0,0}, a3 = {0,0,0,0};

    int e = s;
    for (; e + 16 <= en; e += 16) {
        const int c0 = col_sorted[e + g];
        const int c1 = col_sorted[e + 4 + g];
        const int c2 = col_sorted[e + 8 + g];
        const int c3 = col_sorted[e + 12 + g];
        const ushort4 t0 = xb4[(size_t)c0 * 16 + q];
        const ushort4 t1 = xb4[(size_t)c1 * 16 + q];
        const ushort4 t2 = xb4[(size_t)c2 * 16 + q];
        const ushort4 t3 = xb4[(size_t)c3 * 16 + q];
        a0.x += bf2f(t0.x); a0.y += bf2f(t0.y); a0.z += bf2f(t0.z); a0.w += bf2f(t0.w);
        a1.x += bf2f(t1.x); a1.y += bf2f(t1.y); a1.z += bf2f(t1.z); a1.w += bf2f(t1.w);
        a2.x += bf2f(t2.x); a2.y += bf2f(t2.y); a2.z += bf2f(t2.z); a2.w += bf2f(t2.w);
        a3.x += bf2f(t3.x); a3.y += bf2f(t3.y); a3.z += bf2f(t3.z); a3.w += bf2f(t3.w);
    }
    for (; e + 4 <= en; e += 4) {
        const int c = col_sorted[e + g];
        const ushort4 t = xb4[(size_t)c * 16 + q];
        a0.x += bf2f(t.x); a0.y += bf2f(t.y); a0.z += bf2f(t.z); a0.w += bf2f(t.w);
    }
    if (e + g < en) {
        const int c = col_sorted[e + g];
        const ushort4 t = xb4[(size_t)c * 16 + q];
        a1.x += bf2f(t.x); a1.y += bf2f(t.y); a1.z += bf2f(t.z); a1.w += bf2f(t.w);
    }

    float4 v;
    v.x = (a0.x + a1.x) + (a2.x + a3.x);
    v.y = (a0.y + a1.y) + (a2.y + a3.y);
    v.z = (a0.z + a1.z) + (a2.z + a3.z);
    v.w = (a0.w + a1.w) + (a2.w + a3.w);
    v.x += __shfl_xor(v.x, 16, 64);
    v.y += __shfl_xor(v.y, 16, 64);
    v.z += __shfl_xor(v.z, 16, 64);
    v.w += __shfl_xor(v.w, 16, 64);
    v.x += __shfl_xor(v.x, 32, 64);
    v.y += __shfl_xor(v.y, 32, 64);
    v.z += __shfl_xor(v.z, 32, 64);
    v.w += __shfl_xor(v.w, 32, 64);
    v.x += bf2f(uself.x);
    v.y += bf2f(uself.y);
    v.z += bf2f(uself.z);
    v.w += bf2f(uself.w);

    if (g == 0) {
        ushort4 o;
        o.x = f2bf(v.x); o.y = f2bf(v.y); o.z = f2bf(v.z); o.w = f2bf(v.w);
        aggb4[(size_t)r * 16 + q] = o;
    }
}

// ---------------- Kernel B: MFMA bf16 MLP, weights staged in LDS --------------
// Weights staged TRANSPOSED [col][k] as bf16 with 72-short row stride (144 B,
// 16B-aligned rows); fragments = single ds_read_b128 each, start banks uniform.
__global__ __launch_bounds__(256) void mlp_kernel(
    unsigned short* io,                         // bf16 agg -> bf16 h2 (ws)
    const float* __restrict__ W1,
    const float* __restrict__ b1,
    const float* __restrict__ W2,
    const float* __restrict__ b2,
    float* __restrict__ partial,                // [128][NP]
    int nNodes, int NP)
{
    __shared__ unsigned short sW1t[64][72];   // [col][k] bf16, padded
    __shared__ unsigned short sW2t[64][72];
    __shared__ float sH[4][16][68];           // per-wave h1 [node][feat], padded
    __shared__ float sSum[4][64];
    __shared__ float sSq[4][64];

    const int tid  = threadIdx.x;

    // ---- stage both weight matrices (coalesced f32 read -> transposed bf16) ----
    {
        const float4* w14 = (const float4*)W1;
        const float4* w24 = (const float4*)W2;
        #pragma unroll
        for (int i = 0; i < 4; ++i) {
            const int f4idx = i * 256 + tid;      // 0..1023
            const int k     = f4idx >> 4;         // W row (k index)
            const int col0  = (f4idx & 15) * 4;   // W col
            const float4 v1 = w14[f4idx];
            sW1t[col0 + 0][k] = f2bf(v1.x);
            sW1t[col0 + 1][k] = f2bf(v1.y);
            sW1t[col0 + 2][k] = f2bf(v1.z);
            sW1t[col0 + 3][k] = f2bf(v1.w);
            const float4 v2 = w24[f4idx];
            sW2t[col0 + 0][k] = f2bf(v2.x);
            sW2t[col0 + 1][k] = f2bf(v2.y);
            sW2t[col0 + 2][k] = f2bf(v2.z);
            sW2t[col0 + 3][k] = f2bf(v2.w);
        }
    }
    __syncthreads();

    const int lane = tid & 63;
    const int w    = tid >> 6;
    const int nb   = lane & 15;
    const int kg   = lane >> 4;
    const int kb   = kg * 8;

    // fragments: contiguous 8 bf16 -> one b128 per (s,c)
    bf16x8 w1f[2][4], w2f[2][4];
    #pragma unroll
    for (int s = 0; s < 2; ++s) {
        #pragma unroll
        for (int c = 0; c < 4; ++c) {
            w1f[s][c] = *reinterpret_cast<const bf16x8*>(&sW1t[c * 16 + nb][s * 32 + kb]);
            w2f[s][c] = *reinterpret_cast<const bf16x8*>(&sW2t[c * 16 + nb][s * 32 + kb]);
        }
    }

    const int node0 = blockIdx.x * 64 + w * 16;

    int an = node0 + nb;
    if (an >= nNodes) an = nNodes - 1;
    const unsigned short* arow = io + (size_t)an * 64;
    bf16x8 a[2];
    a[0] = *reinterpret_cast<const bf16x8*>(arow + kb);
    a[1] = *reinterpret_cast<const bf16x8*>(arow + 32 + kb);

    #pragma unroll
    for (int c = 0; c < 4; ++c) {
        const float bias = b1[c * 16 + nb];
        f32x4 acc = {bias, bias, bias, bias};
        acc = __builtin_amdgcn_mfma_f32_16x16x32_bf16(a[0], w1f[0][c], acc, 0, 0, 0);
        acc = __builtin_amdgcn_mfma_f32_16x16x32_bf16(a[1], w1f[1][c], acc, 0, 0, 0);
        #pragma unroll
        for (int r = 0; r < 4; ++r)
            sH[w][kg * 4 + r][c * 16 + nb] = fmaxf(acc[r], 0.0f);
    }
    __syncthreads();

    bf16x8 h[2];
    #pragma unroll
    for (int s = 0; s < 2; ++s)
        #pragma unroll
        for (int e = 0; e < 8; ++e)
            h[s][e] = (short)f2bf(sH[w][nb][s * 32 + kb + e]);

    #pragma unroll
    for (int c = 0; c < 4; ++c) {
        const float bias = b2[c * 16 + nb];
        f32x4 acc = {bias, bias, bias, bias};
        acc = __builtin_amdgcn_mfma_f32_16x16x32_bf16(h[0], w2f[0][c], acc, 0, 0, 0);
        acc = __builtin_amdgcn_mfma_f32_16x16x32_bf16(h[1], w2f[1][c], acc, 0, 0, 0);
        float sv = 0.0f, sq = 0.0f;
        #pragma unroll
        for (int r = 0; r < 4; ++r) {
            const int node = node0 + kg * 4 + r;
            const float vv = fmaxf(acc[r], 0.0f);
            if (node < nNodes) {
                io[(size_t)node * 64 + c * 16 + nb] = f2bf(vv);
                sv += vv;
                sq = fmaf(vv, vv, sq);
            }
        }
        sv += __shfl_xor(sv, 16, 64);
        sv += __shfl_xor(sv, 32, 64);
        sq += __shfl_xor(sq, 16, 64);
        sq += __shfl_xor(sq, 32, 64);
        if (kg == 0) {
            sSum[w][c * 16 + nb] = sv;
            sSq[w][c * 16 + nb] = sq;
        }
    }
    __syncthreads();

    if (tid < 128) {
        const int f = tid & 63;
        float t;
        if (tid < 64) t = sSum[0][f] + sSum[1][f] + sSum[2][f] + sSum[3][f];
        else          t = sSq[0][f] + sSq[1][f] + sSq[2][f] + sSq[3][f];
        partial[(size_t)tid * NP + blockIdx.x] = t;
    }
}

// ---------------- Kernel C1b: reduce partials -> scale/shift (deterministic) --
__global__ __launch_bounds__(256) void stats_reduce(
    const float* __restrict__ partial,   // [128][NP]
    const float* __restrict__ gamma,
    const float* __restrict__ beta,
    float* __restrict__ ss,              // [128]: scale | shift
    int NP, float invN)
{
    __shared__ float rs[256];
    __shared__ float rq[256];
    const int f = blockIdx.x;            // 0..63
    const int t = threadIdx.x;
    float as = 0.0f, aq = 0.0f;
    for (int i = t; i < NP; i += 256) {
        as += partial[(size_t)f * NP + i];
        aq += partial[(size_t)(64 + f) * NP + i];
    }
    rs[t] = as;
    rq[t] = aq;
    __syncthreads();
    for (int off = 128; off > 0; off >>= 1) {
        if (t < off) { rs[t] += rs[t + off]; rq[t] += rq[t + off]; }
        __syncthreads();
    }
    if (t == 0) {
        const float mean = rs[0] * invN;
        const float var  = rq[0] * invN - mean * mean;
        const float inv  = rsqrtf(var + BN_EPS);
        const float g    = gamma[f];
        ss[f]      = inv * g;
        ss[64 + f] = beta[f] - mean * inv * g;
    }
}

// ---------------- Kernel C2: BN apply — bf16 h2 in, f32 out -------------------
__global__ __launch_bounds__(256) void bn_normalize_kernel(
    const ushort4* __restrict__ h2b,     // bf16 h2 (ws)
    const float* __restrict__ ss,        // [128]: scale | shift
    float4* __restrict__ out4,           // d_out
    int nNodes)
{
    __shared__ float sscale[F];
    __shared__ float sshift[F];
    if (threadIdx.x < F) {
        sscale[threadIdx.x] = ss[threadIdx.x];
        sshift[threadIdx.x] = ss[64 + threadIdx.x];
    }
    __syncthreads();

    const int total = nNodes * 16;       // ushort4 units (4 feats each)
    const int stride = gridDim.x * blockDim.x;
    for (int i = blockIdx.x * blockDim.x + threadIdx.x; i < total; i += stride) {
        const int f0 = (i & 15) * 4;
        const ushort4 u = h2b[i];
        float4 v;
        v.x = fmaf(bf2f(u.x), sscale[f0 + 0], sshift[f0 + 0]);
        v.y = fmaf(bf2f(u.y), sscale[f0 + 1], sshift[f0 + 1]);
        v.z = fmaf(bf2f(u.z), sscale[f0 + 2], sshift[f0 + 2]);
        v.w = fmaf(bf2f(u.w), sscale[f0 + 3], sshift[f0 + 3]);
        out4[i] = v;
    }
}

extern "C" void kernel_launch(void* const* d_in, const int* in_sizes, int n_in,
                              void* d_out, int out_size, void* d_ws, size_t ws_size,
                              hipStream_t stream)
{
    const float* x     = (const float*)d_in[0];
    const int*   eidx  = (const int*)d_in[1];   // [2, E]: row then col
    const float* W1    = (const float*)d_in[2];
    const float* b1    = (const float*)d_in[3];
    const float* W2    = (const float*)d_in[4];
    const float* b2    = (const float*)d_in[5];
    const float* gamma = (const float*)d_in[6];
    const float* beta  = (const float*)d_in[7];

    const int nNodes = in_sizes[0] / F;
    const int nEdges = in_sizes[1] / 2;
    const int* row = eidx;
    const int* col = eidx + nEdges;

    const int NB = (nNodes + 127) >> BSH;
    const int C  = (nEdges + NBLK - 1) / NBLK;
    const int NP = (nNodes + 63) / 64;         // mlp blocks

    // workspace layout; 256B-aligned. LIFETIME-SIZED UNIONS:
    //   cntX   = cnt[NBLK*NB] (P1-P3)  UNION  col_sorted[nEdges+16] (P4-gather)
    //   packedX= packed[nEdges] (P3-P4) UNION  agg/h2 bf16 [nNodes*64] (gather-bn)
    char* wsp = (char*)d_ws;
    auto alloc = [&](size_t bytes) -> char* {
        char* p = wsp;
        wsp += (bytes + 255) & ~(size_t)255;
        return p;
    };
    size_t cnt_bytes = (size_t)NBLK * NB * 4;
    size_t cs_bytes  = ((size_t)nEdges + 16) * 4;
    size_t pk_bytes  = (size_t)nEdges * 4;
    size_t ag_bytes  = (size_t)nNodes * F * 2;

    float*    ss         = (float*)alloc(128 * 4);
    float*    partial    = (float*)alloc((size_t)128 * NP * 4);
    int*      gstart     = (int*)alloc((size_t)(NB + 1) * 4);
    int*      colsum     = (int*)alloc((size_t)NB * 4);
    int*      starts     = (int*)alloc((size_t)(nNodes + 1) * 4);
    char*     cntX       = alloc(cnt_bytes > cs_bytes ? cnt_bytes : cs_bytes);
    int*      cnt        = (int*)cntX;
    int*      col_sorted = (int*)cntX;
    char*     packedX    = alloc(pk_bytes > ag_bytes ? pk_bytes : ag_bytes);
    unsigned* packed     = (unsigned*)packedX;
    unsigned short* aggbf = (unsigned short*)packedX;

    ushort4* xb4 = (ushort4*)d_out;    // bf16 x in d_out until gather completes
    float4* out4 = (float4*)d_out;

    p1_count  <<<NBLK, 256, 0, stream>>>((const float4*)x, xb4, row, col, cnt,
                                         nEdges, NB, C, nNodes * 16);
    p2a_colscan<<<NB, 256, 0, stream>>>(cnt, colsum, NB);
    p3_scatter<<<NBLK, 256, 0, stream>>>(row, col, cnt, colsum, gstart,
                                         starts + nNodes, packed, nEdges, NB, C);
    p4_sort   <<<NB, 256, 0, stream>>>(packed, gstart, starts, col_sorted, nNodes, NB);

    gather_kernel<<<(nNodes + 3) / 4, 256, 0, stream>>>(
        (const ushort4*)xb4, starts, col_sorted, (ushort4*)aggbf, nNodes);

    mlp_kernel<<<NP, 256, 0, stream>>>(
        aggbf, W1, b1, W2, b2, partial, nNodes, NP);

    stats_reduce<<<64, 256, 0, stream>>>(partial, gamma, beta, ss, NP,
                                         1.0f / (float)nNodes);

    bn_normalize_kernel<<<2048, 256, 0, stream>>>(
        (const ushort4*)aggbf, ss, out4, nNodes);
}